// Round 1
// baseline (133.804 us; speedup 1.0000x reference)
//
#include <hip/hip_runtime.h>
#include <hip/hip_bf16.h>

// Problem constants
#define BSZ   2048
#define DIMZ  32
#define NNv   40
#define MMv   40
#define OOv   200
#define KKv   1600            // NN*MM
#define BD_TOTAL 65536        // BS*DIM
#define OPAD  208             // 13 col-tiles of 16
#define NSTEPS 50             // KK / 32
#define CHUNK_SLOTS 832       // OPAD * 4 (16B slots)
#define CHUNK_BYTES 13312     // CHUNK_SLOTS * 16
#define XPAD 44               // fp32 row stride for x tile in LDS (bank-quad permutation)
#define YPAD 44               // fp32 row stride for y tile in LDS

typedef __attribute__((ext_vector_type(8))) short short8;
typedef __attribute__((ext_vector_type(4))) float floatx4;

// ---------------------------------------------------------------------------
// Pre-kernel: W [200][1600] fp32  ->  Wb bf16, chunk-major + swizzled.
// Wb element index (bf16 units): idx = c*CHUNK_SLOTS*8 + slot*8 + j
//   slot = o*4 + (kg ^ ((o>>1)&3)),  k = c*32 + kg*8 + j,  o in [0,208) (o>=200 -> 0)
// ---------------------------------------------------------------------------
__global__ void wb_convert_kernel(const float* __restrict__ W,
                                  unsigned short* __restrict__ Wb) {
    int idx = blockIdx.x * 256 + threadIdx.x;
    if (idx >= NSTEPS * CHUNK_SLOTS * 8) return;
    int j    = idx & 7;
    int slot = (idx >> 3) % CHUNK_SLOTS;
    int c    = (idx >> 3) / CHUNK_SLOTS;
    int o    = slot >> 2;
    int kgs  = slot & 3;
    int kg   = kgs ^ ((o >> 1) & 3);
    int k    = c * 32 + kg * 8 + j;
    float v  = (o < OOv) ? W[o * KKv + k] : 0.0f;
    __hip_bfloat16 h = __float2bfloat16(v);
    Wb[idx] = *reinterpret_cast<unsigned short*>(&h);
}

__device__ __forceinline__ short f2bf(float f) {
    __hip_bfloat16 h = __float2bfloat16(f);
    return *reinterpret_cast<short*>(&h);
}

// Async global->LDS stage of one 13312B W chunk (13 wave-units of 1KB).
__device__ __forceinline__ void stageB(const unsigned short* __restrict__ Wb,
                                       int step, unsigned char* dst,
                                       int wave, int lane) {
    const char* src = (const char*)Wb + (size_t)step * CHUNK_BYTES;
    for (int c = wave; c < 13; c += 4) {
        int off = c * 1024 + lane * 16;
        __builtin_amdgcn_global_load_lds(
            (const __attribute__((address_space(1))) unsigned int*)(src + off),
            (__attribute__((address_space(3))) unsigned int*)(dst + off),
            16, 0, 0);
    }
}

// ---------------------------------------------------------------------------
// Main kernel: 512 blocks x 256 threads. Block = 128 rows x 208 cols.
// Wave layout: rowhalf = wave&1 (64 rows), colgrp = wave>>1 (7 or 6 col-tiles).
// ---------------------------------------------------------------------------
__global__ __launch_bounds__(256, 2) void cin_mfma_kernel(
        const float* __restrict__ X, const float* __restrict__ Y,
        const unsigned short* __restrict__ Wb, float* __restrict__ Out) {
    // LDS: B double buffer (2x13312) + x tile (128*44*4) + y tile (128*44*4) = 71680 B
    __shared__ __align__(16) unsigned char smem[2 * CHUNK_BYTES + 128 * XPAD * 4 + 128 * YPAD * 4];
    unsigned char* bbuf0 = smem;
    unsigned char* bbuf1 = smem + CHUNK_BYTES;
    float* xlds = (float*)(smem + 2 * CHUNK_BYTES);
    float* ylds = (float*)(smem + 2 * CHUNK_BYTES + 128 * XPAD * 4);

    const int tid     = threadIdx.x;
    const int wave    = tid >> 6;
    const int lane    = tid & 63;
    const int li      = lane & 15;
    const int kg      = lane >> 4;
    const int rowhalf = wave & 1;
    const int colgrp  = wave >> 1;
    const int ntiles  = colgrp ? 6 : 7;
    const int obase   = colgrp * 112;
    const long blockbase = (long)blockIdx.x * 128;

    // ---- prologue: stage x,y tiles (each 128 rows x 40 fp32, globally contiguous)
    const float* xg = X + blockbase * NNv;
    const float* yg = Y + blockbase * MMv;
    for (int i = tid; i < 1280; i += 256) {      // 1280 float4s = 5120 floats
        int r  = i / 10;
        int c4 = (i % 10) * 4;                   // 40 % 4 == 0: never crosses a row
        floatx4 vx = *(const floatx4*)(xg + i * 4);
        *(floatx4*)(xlds + r * XPAD + c4) = vx;
        floatx4 vy = *(const floatx4*)(yg + i * 4);
        *(floatx4*)(ylds + r * YPAD + c4) = vy;
    }
    stageB(Wb, 0, bbuf0, wave, lane);
    __syncthreads();

    floatx4 acc[4][7];
#pragma unroll
    for (int rt = 0; rt < 4; ++rt)
#pragma unroll
        for (int ct = 0; ct < 7; ++ct)
            acc[rt][ct] = (floatx4){0.f, 0.f, 0.f, 0.f};

    // per-lane incremental k decomposition: k = step*32 + kg*8 (+j); s = k%40, n = k/40
    int s = kg * 8;
    int n = 0;
    // per-lane constant byte offset for B-frag reads (swizzled slot addressing)
    const int bfoff = (obase + li) * 64 + ((kg ^ ((li >> 1) & 3)) * 16);
    const int rowb  = rowhalf * 64 + li;

    for (int step = 0; step < NSTEPS; ++step) {
        unsigned char* cur = (step & 1) ? bbuf1 : bbuf0;
        unsigned char* nxt = (step & 1) ? bbuf0 : bbuf1;
        if (step + 1 < NSTEPS) stageB(Wb, step + 1, nxt, wave, lane);

        // B fragments: one ds_read_b128 per col-tile
        short8 bf[7];
#pragma unroll
        for (int ct = 0; ct < 7; ++ct)
            if (ct < ntiles)
                bf[ct] = *(const short8*)(cur + bfoff + ct * 1024);

        // A fragments in registers: A[row][k] = x[row][n] * y[row][s..s+7]
        short8 af[4];
#pragma unroll
        for (int rt = 0; rt < 4; ++rt) {
            int row = rowb + rt * 16;
            float xv = xlds[row * XPAD + n];
            floatx4 y0 = *(const floatx4*)(ylds + row * YPAD + s);
            floatx4 y1 = *(const floatx4*)(ylds + row * YPAD + s + 4);
            short8 a;
            a[0] = f2bf(xv * y0.x); a[1] = f2bf(xv * y0.y);
            a[2] = f2bf(xv * y0.z); a[3] = f2bf(xv * y0.w);
            a[4] = f2bf(xv * y1.x); a[5] = f2bf(xv * y1.y);
            a[6] = f2bf(xv * y1.z); a[7] = f2bf(xv * y1.w);
            af[rt] = a;
        }

#pragma unroll
        for (int ct = 0; ct < 7; ++ct)
            if (ct < ntiles)
#pragma unroll
                for (int rt = 0; rt < 4; ++rt)
                    acc[rt][ct] = __builtin_amdgcn_mfma_f32_16x16x32_bf16(
                        af[rt], bf[ct], acc[rt][ct], 0, 0, 0);

        s += 32;
        if (s >= 40) { s -= 40; ++n; }
        __syncthreads();   // drains staging vmcnt + LDS reads before buffer swap
    }

    // ---- epilogue: C/D layout col = lane&15, row = (lane>>4)*4 + reg  [m89]
#pragma unroll
    for (int rt = 0; rt < 4; ++rt) {
#pragma unroll
        for (int ct = 0; ct < 7; ++ct) {
            if (ct >= ntiles) continue;
            int gcol = obase + ct * 16 + li;
            if (gcol < OOv) {
#pragma unroll
                for (int r4 = 0; r4 < 4; ++r4) {
                    long grow = blockbase + rowhalf * 64 + rt * 16 + kg * 4 + r4;
                    Out[grow * OOv + gcol] = acc[rt][ct][r4];
                }
            }
        }
    }
}

extern "C" void kernel_launch(void* const* d_in, const int* in_sizes, int n_in,
                              void* d_out, int out_size, void* d_ws, size_t ws_size,
                              hipStream_t stream) {
    (void)in_sizes; (void)n_in; (void)out_size; (void)ws_size;
    const float* X = (const float*)d_in[0];
    const float* Y = (const float*)d_in[1];
    const float* W = (const float*)d_in[2];
    float* Out = (float*)d_out;
    unsigned short* Wb = (unsigned short*)d_ws;   // needs 665,600 B of scratch

    // 50*832*8 = 332800 elements -> 1300 blocks of 256
    wb_convert_kernel<<<1300, 256, 0, stream>>>(W, Wb);
    cin_mfma_kernel<<<512, 256, 0, stream>>>(X, Y, Wb, Out);
}